// Round 1
// baseline (955.413 us; speedup 1.0000x reference)
//
#include <hip/hip_runtime.h>
#include <hip/hip_bf16.h>

#define DD 128

typedef __attribute__((ext_vector_type(8))) short bfrag8;
typedef __attribute__((ext_vector_type(4))) float f32x4;

__device__ __forceinline__ float bf16lo(unsigned int u) {
    union { unsigned int i; float f; } c; c.i = u << 16; return c.f;
}
__device__ __forceinline__ float bf16hi(unsigned int u) {
    union { unsigned int i; float f; } c; c.i = u & 0xffff0000u; return c.f;
}
__device__ __forceinline__ float bf16f(unsigned short u) {
    union { unsigned int i; float f; } c; c.i = ((unsigned int)u) << 16; return c.f;
}
__device__ __forceinline__ unsigned short f2bf(float f) {
    union { float f; unsigned int i; } c; c.f = f;
    unsigned int x = c.i;
    unsigned int r = (x + 0x7fffu + ((x >> 16) & 1u)) >> 16;  // RNE
    return (unsigned short)r;
}

// ---------------- setup: degree histogram + feature convert + W convert ----------------
__global__ void k_setup(const int* __restrict__ dst, int* __restrict__ deg, int E,
                        const float* __restrict__ features, float* __restrict__ out0,
                        unsigned int* __restrict__ hb, int total4,
                        const float* __restrict__ W, unsigned short* __restrict__ Wt) {
    int gtid = blockIdx.x * blockDim.x + threadIdx.x;
    int gsz = gridDim.x * blockDim.x;
    for (int i = gtid; i < E; i += gsz) atomicAdd(&deg[dst[i]], 1);
    for (int i = gtid; i < total4; i += gsz) {
        float4 v = ((const float4*)features)[i];
        ((float4*)out0)[i] = v;
        unsigned int lo = (unsigned int)f2bf(v.x) | ((unsigned int)f2bf(v.y) << 16);
        unsigned int hi = (unsigned int)f2bf(v.z) | ((unsigned int)f2bf(v.w) << 16);
        ((uint2*)hb)[i] = make_uint2(lo, hi);
    }
    for (int i = gtid; i < 3 * 128 * 128; i += gsz) {
        int l = i >> 14, r = i & 16383, k = r >> 7, n = r & 127;
        Wt[(l << 14) + n * 128 + k] = f2bf(W[i]);
    }
}

// ---------------- scan stage 1: per-1024-chunk degree sums ----------------
__global__ void k_scan1(const int* __restrict__ deg, int* __restrict__ partials, int Nn) {
    __shared__ int sm[256];
    int tid = threadIdx.x;
    int base = (blockIdx.x << 10) + 4 * tid;
    int s = 0;
    if (base + 3 < Nn) {
        int4 v = *(const int4*)&deg[base];
        s = v.x + v.y + v.z + v.w;
    } else {
        for (int j = 0; j < 4; j++) if (base + j < Nn) s += deg[base + j];
    }
    sm[tid] = s;
    __syncthreads();
    for (int off = 128; off > 0; off >>= 1) {
        if (tid < off) sm[tid] += sm[tid + off];
        __syncthreads();
    }
    if (tid == 0) partials[blockIdx.x] = sm[0];
}

// ---------------- scan stage 2: final row_start ----------------
__global__ void k_scan3(const int* __restrict__ deg, const int* __restrict__ partials,
                        int* __restrict__ row_start, int Nn, int E, int nchunk) {
    __shared__ int sp[256];
    __shared__ int sm[256];
    int tid = threadIdx.x, c = blockIdx.x;
    int p = (tid < nchunk) ? partials[tid] : 0;
    sp[tid] = p;
    __syncthreads();
    for (int off = 1; off < 256; off <<= 1) {
        int t = (tid >= off) ? sp[tid - off] : 0;
        __syncthreads();
        sp[tid] += t;
        __syncthreads();
    }
    int chunkpref = (c == 0) ? 0 : sp[c - 1];

    int base = (c << 10) + 4 * tid;
    int d0 = 0, d1 = 0, d2 = 0, d3 = 0;
    if (base + 3 < Nn) {
        int4 v = *(const int4*)&deg[base];
        d0 = v.x; d1 = v.y; d2 = v.z; d3 = v.w;
    } else {
        if (base + 0 < Nn) d0 = deg[base + 0];
        if (base + 1 < Nn) d1 = deg[base + 1];
        if (base + 2 < Nn) d2 = deg[base + 2];
        if (base + 3 < Nn) d3 = deg[base + 3];
    }
    int ts = d0 + d1 + d2 + d3;
    sm[tid] = ts;
    __syncthreads();
    for (int off = 1; off < 256; off <<= 1) {
        int t = (tid >= off) ? sm[tid - off] : 0;
        __syncthreads();
        sm[tid] += t;
        __syncthreads();
    }
    int run = chunkpref + sm[tid] - ts;
    if (base + 0 < Nn) row_start[base + 0] = run; run += d0;
    if (base + 1 < Nn) row_start[base + 1] = run; run += d1;
    if (base + 2 < Nn) row_start[base + 2] = run; run += d2;
    if (base + 3 < Nn) row_start[base + 3] = run;
    if (c == 0 && tid == 0) row_start[Nn] = E;
}

// ---------------- scatter edges into CSR ----------------
__global__ void k_scatter(const int* __restrict__ src, const int* __restrict__ dst,
                          const int* __restrict__ row_start, int* __restrict__ cursor,
                          int* __restrict__ csr, int E) {
    int i = blockIdx.x * blockDim.x + threadIdx.x;
    if (i < E) {
        int d = dst[i];
        int pos = row_start[d] + atomicAdd(&cursor[d], 1);
        csr[pos] = src[i];
    }
}

// ---------------- fused gather + GEMM: z = (1+eps)h + sum nbr; y = z@W + b (bf16 out) ----
// LDS holds only the 64x128 A-tile (gathered z, bf16). B fragments come straight from
// global: W is 32KB/layer, L2-resident, reused by all 1563 blocks (~50MB L2 reads total).
__launch_bounds__(256)
__global__ void k_gg(const unsigned int* __restrict__ hb, const int* __restrict__ row_start,
                     const int* __restrict__ csr, const float* __restrict__ eps, int layer,
                     const unsigned short* __restrict__ Wt, const float* __restrict__ bias,
                     unsigned short* __restrict__ yb, float* __restrict__ stl, int Nn) {
    __shared__ unsigned short Al[64 * 136];
    int tid = threadIdx.x;
    int m0 = blockIdx.x * 64;
    int wv = tid >> 6, lane = tid & 63;

    // ---- gather phase: wave wv produces A rows 16*wv .. 16*wv+15, lane = feature pair ----
    float e1 = 1.0f + eps[layer];
    for (int r8 = 0; r8 < 16; r8++) {
        int r = (wv << 4) + r8;
        int v = m0 + r;
        unsigned int packed = 0;
        if (v < Nn) {
            unsigned int hs = hb[(size_t)v * 64 + lane];
            float ax = e1 * bf16lo(hs);
            float ay = e1 * bf16hi(hs);
            int beg = row_start[v], end = row_start[v + 1];
            int e = beg;
            for (; e + 7 < end; e += 8) {
                int u0 = csr[e], u1 = csr[e + 1], u2 = csr[e + 2], u3 = csr[e + 3];
                int u4 = csr[e + 4], u5 = csr[e + 5], u6 = csr[e + 6], u7 = csr[e + 7];
                unsigned int h0 = hb[(size_t)u0 * 64 + lane];
                unsigned int h1 = hb[(size_t)u1 * 64 + lane];
                unsigned int h2 = hb[(size_t)u2 * 64 + lane];
                unsigned int h3 = hb[(size_t)u3 * 64 + lane];
                unsigned int h4 = hb[(size_t)u4 * 64 + lane];
                unsigned int h5 = hb[(size_t)u5 * 64 + lane];
                unsigned int h6 = hb[(size_t)u6 * 64 + lane];
                unsigned int h7 = hb[(size_t)u7 * 64 + lane];
                ax += bf16lo(h0) + bf16lo(h1) + bf16lo(h2) + bf16lo(h3)
                    + bf16lo(h4) + bf16lo(h5) + bf16lo(h6) + bf16lo(h7);
                ay += bf16hi(h0) + bf16hi(h1) + bf16hi(h2) + bf16hi(h3)
                    + bf16hi(h4) + bf16hi(h5) + bf16hi(h6) + bf16hi(h7);
            }
            for (; e < end; e++) {
                unsigned int hu = hb[(size_t)csr[e] * 64 + lane];
                ax += bf16lo(hu); ay += bf16hi(hu);
            }
            packed = (unsigned int)f2bf(ax) | ((unsigned int)f2bf(ay) << 16);
        }
        *(unsigned int*)&Al[r * 136 + 2 * lane] = packed;
    }
    __syncthreads();

    // ---- MFMA phase ----
    int tcol = lane & 15, quad = lane >> 4;
    const unsigned short* Wl = Wt + (layer << 14);
    f32x4 acc[4][2];
    #pragma unroll
    for (int a = 0; a < 4; a++)
        #pragma unroll
        for (int b2 = 0; b2 < 2; b2++) acc[a][b2] = (f32x4){0.f, 0.f, 0.f, 0.f};

    #pragma unroll
    for (int kk = 0; kk < 128; kk += 32) {
        int kb = kk + quad * 8;
        bfrag8 af[4], bf[2];
        #pragma unroll
        for (int mt = 0; mt < 4; mt++)
            af[mt] = *(const bfrag8*)&Al[(16 * mt + tcol) * 136 + kb];
        #pragma unroll
        for (int nt = 0; nt < 2; nt++)
            bf[nt] = *(const bfrag8*)&Wl[(32 * wv + 16 * nt + tcol) * 128 + kb];
        #pragma unroll
        for (int mt = 0; mt < 4; mt++)
            #pragma unroll
            for (int nt = 0; nt < 2; nt++)
                acc[mt][nt] = __builtin_amdgcn_mfma_f32_16x16x32_bf16(af[mt], bf[nt], acc[mt][nt], 0, 0, 0);
    }

    // ---- epilogue: bias, bf16 store, BN1 column stats (computed from ROUNDED values) ----
    #pragma unroll
    for (int nt = 0; nt < 2; nt++) {
        int col = 32 * wv + 16 * nt + tcol;
        float bcol = bias[layer * 128 + col];
        float psum = 0.f, psq = 0.f;
        #pragma unroll
        for (int mt = 0; mt < 4; mt++) {
            #pragma unroll
            for (int r = 0; r < 4; r++) {
                int row = m0 + 16 * mt + quad * 4 + r;
                if (row < Nn) {
                    unsigned short u = f2bf(acc[mt][nt][r] + bcol);
                    yb[(size_t)row * 128 + col] = u;
                    float vr = bf16f(u);
                    psum += vr;
                    psq += vr * vr;
                }
            }
        }
        psum += __shfl_xor(psum, 16); psq += __shfl_xor(psq, 16);
        psum += __shfl_xor(psum, 32); psq += __shfl_xor(psq, 32);
        if (lane < 16) {
            atomicAdd(&stl[col], psum);
            atomicAdd(&stl[128 + col], psq);
        }
    }
}

// ---------------- BN2 stats over relu(aff1(y)); BN1 scale/shift derived in-block ----------------
__launch_bounds__(256)
__global__ void k_stats2(const unsigned short* __restrict__ yb, float* __restrict__ stl,
                         const float* __restrict__ g1, const float* __restrict__ b1,
                         int layer, int totalU8, float invN) {
    __shared__ float red[512];
    int tid = threadIdx.x;
    if (tid < 128) {
        float m = stl[tid] * invN;
        float var = stl[128 + tid] * invN - m * m;
        float rstd = rsqrtf(var + 1e-5f);
        float s = g1[layer * 128 + tid] * rstd;
        red[tid] = s;
        red[128 + tid] = b1[layer * 128 + tid] - m * s;
        red[256 + tid] = 0.f;
        red[384 + tid] = 0.f;
    }
    __syncthreads();
    int lane = tid & 63;
    int cbase = (8 * tid) & 127;
    float s1r[8], sh1r[8];
    #pragma unroll
    for (int j = 0; j < 8; j++) { s1r[j] = red[cbase + j]; sh1r[j] = red[128 + cbase + j]; }
    float ps[8], pq[8];
    #pragma unroll
    for (int j = 0; j < 8; j++) { ps[j] = 0.f; pq[j] = 0.f; }
    int gtid = blockIdx.x * 256 + tid;
    int gsz = gridDim.x * 256;
    const uint4* yb4 = (const uint4*)yb;
    for (int i = gtid; i < totalU8; i += gsz) {
        uint4 v = yb4[i];
        float f[8];
        f[0] = bf16lo(v.x); f[1] = bf16hi(v.x);
        f[2] = bf16lo(v.y); f[3] = bf16hi(v.y);
        f[4] = bf16lo(v.z); f[5] = bf16hi(v.z);
        f[6] = bf16lo(v.w); f[7] = bf16hi(v.w);
        #pragma unroll
        for (int j = 0; j < 8; j++) {
            float t = fmaxf(f[j] * s1r[j] + sh1r[j], 0.f);
            ps[j] += t; pq[j] += t * t;
        }
    }
    #pragma unroll
    for (int j = 0; j < 8; j++) {
        ps[j] += __shfl_xor(ps[j], 16);
        pq[j] += __shfl_xor(pq[j], 16);
        ps[j] += __shfl_xor(ps[j], 32);
        pq[j] += __shfl_xor(pq[j], 32);
    }
    if (lane < 16) {
        #pragma unroll
        for (int j = 0; j < 8; j++) {
            atomicAdd(&red[256 + cbase + j], ps[j]);
            atomicAdd(&red[384 + cbase + j], pq[j]);
        }
    }
    __syncthreads();
    if (tid < 128) {
        atomicAdd(&stl[256 + tid], red[256 + tid]);
        atomicAdd(&stl[384 + tid], red[384 + tid]);
    }
}

// ---------------- apply both BNs, write out slab (f32) + bf16 h ----------------
__launch_bounds__(256)
__global__ void k_apply(const unsigned short* __restrict__ yb, const float* __restrict__ stl,
                        const float* __restrict__ g1, const float* __restrict__ b1,
                        const float* __restrict__ g2, const float* __restrict__ b2,
                        int layer, float* __restrict__ outl, unsigned int* __restrict__ hb,
                        int totalU8, float invN) {
    __shared__ float red[512];
    int tid = threadIdx.x;
    if (tid < 128) {
        float m1 = stl[tid] * invN;
        float v1 = stl[128 + tid] * invN - m1 * m1;
        float r1 = rsqrtf(v1 + 1e-5f);
        float s1 = g1[layer * 128 + tid] * r1;
        red[tid] = s1;
        red[128 + tid] = b1[layer * 128 + tid] - m1 * s1;
        float m2 = stl[256 + tid] * invN;
        float v2 = stl[384 + tid] * invN - m2 * m2;
        float r2 = rsqrtf(v2 + 1e-5f);
        float s2 = g2[layer * 128 + tid] * r2;
        red[256 + tid] = s2;
        red[384 + tid] = b2[layer * 128 + tid] - m2 * s2;
    }
    __syncthreads();
    int cbase = (8 * tid) & 127;
    float s1a[8], sh1a[8], s2a[8], sh2a[8];
    #pragma unroll
    for (int j = 0; j < 8; j++) {
        s1a[j]  = red[cbase + j];       sh1a[j] = red[128 + cbase + j];
        s2a[j]  = red[256 + cbase + j]; sh2a[j] = red[384 + cbase + j];
    }
    int gtid = blockIdx.x * 256 + tid;
    int gsz = gridDim.x * 256;
    const uint4* yb4 = (const uint4*)yb;
    for (int i = gtid; i < totalU8; i += gsz) {
        uint4 v = yb4[i];
        float f[8];
        f[0] = bf16lo(v.x); f[1] = bf16hi(v.x);
        f[2] = bf16lo(v.y); f[3] = bf16hi(v.y);
        f[4] = bf16lo(v.z); f[5] = bf16hi(v.z);
        f[6] = bf16lo(v.w); f[7] = bf16hi(v.w);
        float o[8];
        #pragma unroll
        for (int j = 0; j < 8; j++) {
            float t = fmaxf(f[j] * s1a[j] + sh1a[j], 0.f);
            o[j] = fmaxf(t * s2a[j] + sh2a[j], 0.f);
        }
        ((float4*)outl)[2 * i]     = make_float4(o[0], o[1], o[2], o[3]);
        ((float4*)outl)[2 * i + 1] = make_float4(o[4], o[5], o[6], o[7]);
        uint4 hbv;
        hbv.x = (unsigned int)f2bf(o[0]) | ((unsigned int)f2bf(o[1]) << 16);
        hbv.y = (unsigned int)f2bf(o[2]) | ((unsigned int)f2bf(o[3]) << 16);
        hbv.z = (unsigned int)f2bf(o[4]) | ((unsigned int)f2bf(o[5]) << 16);
        hbv.w = (unsigned int)f2bf(o[6]) | ((unsigned int)f2bf(o[7]) << 16);
        ((uint4*)hb)[i] = hbv;
    }
}

extern "C" void kernel_launch(void* const* d_in, const int* in_sizes, int n_in,
                              void* d_out, int out_size, void* d_ws, size_t ws_size,
                              hipStream_t stream) {
    const float* features = (const float*)d_in[0];
    const float* W        = (const float*)d_in[1];
    const float* bias     = (const float*)d_in[2];
    const float* eps      = (const float*)d_in[3];
    const float* g1       = (const float*)d_in[4];
    const float* b1       = (const float*)d_in[5];
    const float* g2       = (const float*)d_in[6];
    const float* b2       = (const float*)d_in[7];
    const int*   src      = (const int*)d_in[8];
    const int*   dst      = (const int*)d_in[9];

    const int Nn = in_sizes[0] / DD;   // 100000
    const int E  = in_sizes[8];        // 1600000
    float* out = (float*)d_out;

    char* w = (char*)d_ws;
    auto alloc = [&](size_t bytes) -> char* {
        char* p = w;
        w += (bytes + 255) & ~(size_t)255;
        return p;
    };
    // zero-span group (contiguous): deg, cursor, stats
    int*   deg    = (int*)alloc((size_t)Nn * 4);
    int*   cursor = (int*)alloc((size_t)Nn * 4);
    float* stats  = (float*)alloc(3 * 512 * 4);   // [3][4][128]
    char*  zero_end = w;
    int* row_start = (int*)alloc((size_t)(Nn + 1) * 4);
    int* partials  = (int*)alloc(1024);
    int* csr       = (int*)alloc((size_t)E * 4);
    unsigned int* hb = (unsigned int*)alloc((size_t)Nn * 64 * 4);
    unsigned short* Wt = (unsigned short*)alloc((size_t)3 * 128 * 128 * 2);
    unsigned short* yb = (unsigned short*)alloc((size_t)Nn * 128 * 2);

    const int total4 = Nn * DD / 4;
    const int totalU8 = Nn * DD / 8;
    const float invN = 1.0f / (float)Nn;
    const int nchunk = (Nn + 1023) / 1024;   // 98

    hipMemsetAsync(deg, 0, (size_t)(zero_end - (char*)deg), stream);

    k_setup<<<(E + 255) / 256, 256, 0, stream>>>(dst, deg, E, features, out, hb, total4, W, Wt);
    k_scan1<<<nchunk, 256, 0, stream>>>(deg, partials, Nn);
    k_scan3<<<nchunk, 256, 0, stream>>>(deg, partials, row_start, Nn, E, nchunk);
    k_scatter<<<(E + 255) / 256, 256, 0, stream>>>(src, dst, row_start, cursor, csr, E);

    for (int l = 0; l < 3; l++) {
        float* stl = stats + l * 512;
        float* outl = out + (size_t)(l + 1) * Nn * DD;
        k_gg<<<(Nn + 63) / 64, 256, 0, stream>>>(hb, row_start, csr, eps, l, Wt, bias, yb, stl, Nn);
        k_stats2<<<512, 256, 0, stream>>>(yb, stl, g1, b1, l, totalU8, invN);
        k_apply<<<1024, 256, 0, stream>>>(yb, stl, g1, b1, g2, b2, l, outl, hb, totalU8, invN);
    }
}

// Round 2
// 863.837 us; speedup vs baseline: 1.1060x; 1.1060x over previous
//
#include <hip/hip_runtime.h>
#include <hip/hip_bf16.h>

#define DD 128

typedef __attribute__((ext_vector_type(8))) short bfrag8;
typedef __attribute__((ext_vector_type(4))) float f32x4;

__device__ __forceinline__ float bf16lo(unsigned int u) {
    union { unsigned int i; float f; } c; c.i = u << 16; return c.f;
}
__device__ __forceinline__ float bf16hi(unsigned int u) {
    union { unsigned int i; float f; } c; c.i = u & 0xffff0000u; return c.f;
}
__device__ __forceinline__ float bf16f(unsigned short u) {
    union { unsigned int i; float f; } c; c.i = ((unsigned int)u) << 16; return c.f;
}
__device__ __forceinline__ unsigned short f2bf(float f) {
    union { float f; unsigned int i; } c; c.f = f;
    unsigned int x = c.i;
    unsigned int r = (x + 0x7fffu + ((x >> 16) & 1u)) >> 16;  // RNE
    return (unsigned short)r;
}

// ---------------- setup: degree histogram + feature convert + W convert ----------------
__global__ void k_setup(const int* __restrict__ dst, int* __restrict__ deg, int E,
                        const float* __restrict__ features, float* __restrict__ out0,
                        unsigned int* __restrict__ hb, int total4,
                        const float* __restrict__ W, unsigned short* __restrict__ Wt) {
    int gtid = blockIdx.x * blockDim.x + threadIdx.x;
    int gsz = gridDim.x * blockDim.x;
    for (int i = gtid; i < E; i += gsz) atomicAdd(&deg[dst[i]], 1);
    for (int i = gtid; i < total4; i += gsz) {
        float4 v = ((const float4*)features)[i];
        ((float4*)out0)[i] = v;
        unsigned int lo = (unsigned int)f2bf(v.x) | ((unsigned int)f2bf(v.y) << 16);
        unsigned int hi = (unsigned int)f2bf(v.z) | ((unsigned int)f2bf(v.w) << 16);
        ((uint2*)hb)[i] = make_uint2(lo, hi);
    }
    for (int i = gtid; i < 3 * 128 * 128; i += gsz) {
        int l = i >> 14, r = i & 16383, k = r >> 7, n = r & 127;
        Wt[(l << 14) + n * 128 + k] = f2bf(W[i]);
    }
}

// ---------------- scan stage 1: per-1024-chunk degree sums ----------------
__global__ void k_scan1(const int* __restrict__ deg, int* __restrict__ partials, int Nn) {
    __shared__ int sm[256];
    int tid = threadIdx.x;
    int base = (blockIdx.x << 10) + 4 * tid;
    int s = 0;
    if (base + 3 < Nn) {
        int4 v = *(const int4*)&deg[base];
        s = v.x + v.y + v.z + v.w;
    } else {
        for (int j = 0; j < 4; j++) if (base + j < Nn) s += deg[base + j];
    }
    sm[tid] = s;
    __syncthreads();
    for (int off = 128; off > 0; off >>= 1) {
        if (tid < off) sm[tid] += sm[tid + off];
        __syncthreads();
    }
    if (tid == 0) partials[blockIdx.x] = sm[0];
}

// ---------------- scan stage 2: final row_start ----------------
__global__ void k_scan3(const int* __restrict__ deg, const int* __restrict__ partials,
                        int* __restrict__ row_start, int Nn, int E, int nchunk) {
    __shared__ int sp[256];
    __shared__ int sm[256];
    int tid = threadIdx.x, c = blockIdx.x;
    int p = (tid < nchunk) ? partials[tid] : 0;
    sp[tid] = p;
    __syncthreads();
    for (int off = 1; off < 256; off <<= 1) {
        int t = (tid >= off) ? sp[tid - off] : 0;
        __syncthreads();
        sp[tid] += t;
        __syncthreads();
    }
    int chunkpref = (c == 0) ? 0 : sp[c - 1];

    int base = (c << 10) + 4 * tid;
    int d0 = 0, d1 = 0, d2 = 0, d3 = 0;
    if (base + 3 < Nn) {
        int4 v = *(const int4*)&deg[base];
        d0 = v.x; d1 = v.y; d2 = v.z; d3 = v.w;
    } else {
        if (base + 0 < Nn) d0 = deg[base + 0];
        if (base + 1 < Nn) d1 = deg[base + 1];
        if (base + 2 < Nn) d2 = deg[base + 2];
        if (base + 3 < Nn) d3 = deg[base + 3];
    }
    int ts = d0 + d1 + d2 + d3;
    sm[tid] = ts;
    __syncthreads();
    for (int off = 1; off < 256; off <<= 1) {
        int t = (tid >= off) ? sm[tid - off] : 0;
        __syncthreads();
        sm[tid] += t;
        __syncthreads();
    }
    int run = chunkpref + sm[tid] - ts;
    if (base + 0 < Nn) row_start[base + 0] = run; run += d0;
    if (base + 1 < Nn) row_start[base + 1] = run; run += d1;
    if (base + 2 < Nn) row_start[base + 2] = run; run += d2;
    if (base + 3 < Nn) row_start[base + 3] = run;
    if (c == 0 && tid == 0) row_start[Nn] = E;
}

// ---------------- scatter edges into CSR ----------------
__global__ void k_scatter(const int* __restrict__ src, const int* __restrict__ dst,
                          const int* __restrict__ row_start, int* __restrict__ cursor,
                          int* __restrict__ csr, int E) {
    int i = blockIdx.x * blockDim.x + threadIdx.x;
    if (i < E) {
        int d = dst[i];
        int pos = row_start[d] + atomicAdd(&cursor[d], 1);
        csr[pos] = src[i];
    }
}

// ---------------- gather: z = (1+eps)*h + sum_{u in N(v)} h_u  (1 wave per node) ----------------
__global__ void k_gather(const unsigned int* __restrict__ hb, const int* __restrict__ row_start,
                         const int* __restrict__ csr, const float* __restrict__ eps, int layer,
                         unsigned int* __restrict__ zb, int Nn) {
    int wv = threadIdx.x >> 6, lane = threadIdx.x & 63;
    int v = blockIdx.x * 4 + wv;
    if (v >= Nn) return;
    float e1 = 1.0f + eps[layer];
    unsigned int hs = hb[(size_t)v * 64 + lane];
    float ax = e1 * bf16lo(hs);
    float ay = e1 * bf16hi(hs);
    int beg = row_start[v], end = row_start[v + 1];
    int e = beg;
    for (; e + 7 < end; e += 8) {
        int u0 = csr[e], u1 = csr[e + 1], u2 = csr[e + 2], u3 = csr[e + 3];
        int u4 = csr[e + 4], u5 = csr[e + 5], u6 = csr[e + 6], u7 = csr[e + 7];
        unsigned int h0 = hb[(size_t)u0 * 64 + lane];
        unsigned int h1 = hb[(size_t)u1 * 64 + lane];
        unsigned int h2 = hb[(size_t)u2 * 64 + lane];
        unsigned int h3 = hb[(size_t)u3 * 64 + lane];
        unsigned int h4 = hb[(size_t)u4 * 64 + lane];
        unsigned int h5 = hb[(size_t)u5 * 64 + lane];
        unsigned int h6 = hb[(size_t)u6 * 64 + lane];
        unsigned int h7 = hb[(size_t)u7 * 64 + lane];
        ax += bf16lo(h0) + bf16lo(h1) + bf16lo(h2) + bf16lo(h3)
            + bf16lo(h4) + bf16lo(h5) + bf16lo(h6) + bf16lo(h7);
        ay += bf16hi(h0) + bf16hi(h1) + bf16hi(h2) + bf16hi(h3)
            + bf16hi(h4) + bf16hi(h5) + bf16hi(h6) + bf16hi(h7);
    }
    for (; e < end; e++) {
        unsigned int hu = hb[(size_t)csr[e] * 64 + lane];
        ax += bf16lo(hu); ay += bf16hi(hu);
    }
    zb[(size_t)v * 64 + lane] = (unsigned int)f2bf(ax) | ((unsigned int)f2bf(ay) << 16);
}

// ---------------- GEMM: y = z @ W + b (bf16 out), fused BN1 column stats ----------------
// LDS holds only the 64x128 A-tile. B fragments straight from global (W L2-resident).
__launch_bounds__(256)
__global__ void k_gemm(const unsigned short* __restrict__ zb, const unsigned short* __restrict__ Wt,
                       const float* __restrict__ bias, int layer, unsigned short* __restrict__ yb,
                       float* __restrict__ stl, int Nn) {
    __shared__ unsigned short Al[64 * 136];
    int tid = threadIdx.x;
    int m0 = blockIdx.x * 64;
    #pragma unroll
    for (int p = 0; p < 4; p++) {
        int slot = p * 256 + tid;
        int r = slot >> 4, c = slot & 15;
        int grow = m0 + r;
        uint4 val = make_uint4(0, 0, 0, 0);
        if (grow < Nn) val = *(const uint4*)&zb[(size_t)grow * 128 + c * 8];
        *(uint4*)&Al[r * 136 + c * 8] = val;
    }
    __syncthreads();

    int lane = tid & 63, wv = tid >> 6;
    int tcol = lane & 15, quad = lane >> 4;
    const unsigned short* Wl = Wt + (layer << 14);
    f32x4 acc[4][2];
    #pragma unroll
    for (int a = 0; a < 4; a++)
        #pragma unroll
        for (int b2 = 0; b2 < 2; b2++) acc[a][b2] = (f32x4){0.f, 0.f, 0.f, 0.f};

    #pragma unroll
    for (int kk = 0; kk < 128; kk += 32) {
        int kb = kk + quad * 8;
        bfrag8 af[4], bf[2];
        #pragma unroll
        for (int mt = 0; mt < 4; mt++)
            af[mt] = *(const bfrag8*)&Al[(16 * mt + tcol) * 136 + kb];
        #pragma unroll
        for (int nt = 0; nt < 2; nt++)
            bf[nt] = *(const bfrag8*)&Wl[(32 * wv + 16 * nt + tcol) * 128 + kb];
        #pragma unroll
        for (int mt = 0; mt < 4; mt++)
            #pragma unroll
            for (int nt = 0; nt < 2; nt++)
                acc[mt][nt] = __builtin_amdgcn_mfma_f32_16x16x32_bf16(af[mt], bf[nt], acc[mt][nt], 0, 0, 0);
    }

    // epilogue: bias, bf16 store, BN1 column stats (computed from ROUNDED values)
    #pragma unroll
    for (int nt = 0; nt < 2; nt++) {
        int col = 32 * wv + 16 * nt + tcol;
        float bcol = bias[layer * 128 + col];
        float psum = 0.f, psq = 0.f;
        #pragma unroll
        for (int mt = 0; mt < 4; mt++) {
            #pragma unroll
            for (int r = 0; r < 4; r++) {
                int row = m0 + 16 * mt + quad * 4 + r;
                if (row < Nn) {
                    unsigned short u = f2bf(acc[mt][nt][r] + bcol);
                    yb[(size_t)row * 128 + col] = u;
                    float vr = bf16f(u);
                    psum += vr;
                    psq += vr * vr;
                }
            }
        }
        psum += __shfl_xor(psum, 16); psq += __shfl_xor(psq, 16);
        psum += __shfl_xor(psum, 32); psq += __shfl_xor(psq, 32);
        if (lane < 16) {
            atomicAdd(&stl[col], psum);
            atomicAdd(&stl[128 + col], psq);
        }
    }
}

// ---------------- BN2 stats over relu(aff1(y)); BN1 scale/shift derived in-block ----------------
__launch_bounds__(256)
__global__ void k_stats2(const unsigned short* __restrict__ yb, float* __restrict__ stl,
                         const float* __restrict__ g1, const float* __restrict__ b1,
                         int layer, int totalU8, float invN) {
    __shared__ float red[512];
    int tid = threadIdx.x;
    if (tid < 128) {
        float m = stl[tid] * invN;
        float var = stl[128 + tid] * invN - m * m;
        float rstd = rsqrtf(var + 1e-5f);
        float s = g1[layer * 128 + tid] * rstd;
        red[tid] = s;
        red[128 + tid] = b1[layer * 128 + tid] - m * s;
        red[256 + tid] = 0.f;
        red[384 + tid] = 0.f;
    }
    __syncthreads();
    int lane = tid & 63;
    int cbase = (8 * tid) & 127;
    float s1r[8], sh1r[8];
    #pragma unroll
    for (int j = 0; j < 8; j++) { s1r[j] = red[cbase + j]; sh1r[j] = red[128 + cbase + j]; }
    float ps[8], pq[8];
    #pragma unroll
    for (int j = 0; j < 8; j++) { ps[j] = 0.f; pq[j] = 0.f; }
    int gtid = blockIdx.x * 256 + tid;
    int gsz = gridDim.x * 256;
    const uint4* yb4 = (const uint4*)yb;
    for (int i = gtid; i < totalU8; i += gsz) {
        uint4 v = yb4[i];
        float f[8];
        f[0] = bf16lo(v.x); f[1] = bf16hi(v.x);
        f[2] = bf16lo(v.y); f[3] = bf16hi(v.y);
        f[4] = bf16lo(v.z); f[5] = bf16hi(v.z);
        f[6] = bf16lo(v.w); f[7] = bf16hi(v.w);
        #pragma unroll
        for (int j = 0; j < 8; j++) {
            float t = fmaxf(f[j] * s1r[j] + sh1r[j], 0.f);
            ps[j] += t; pq[j] += t * t;
        }
    }
    #pragma unroll
    for (int j = 0; j < 8; j++) {
        ps[j] += __shfl_xor(ps[j], 16);
        pq[j] += __shfl_xor(pq[j], 16);
        ps[j] += __shfl_xor(ps[j], 32);
        pq[j] += __shfl_xor(pq[j], 32);
    }
    if (lane < 16) {
        #pragma unroll
        for (int j = 0; j < 8; j++) {
            atomicAdd(&red[256 + cbase + j], ps[j]);
            atomicAdd(&red[384 + cbase + j], pq[j]);
        }
    }
    __syncthreads();
    if (tid < 128) {
        atomicAdd(&stl[256 + tid], red[256 + tid]);
        atomicAdd(&stl[384 + tid], red[384 + tid]);
    }
}

// ---------------- apply both BNs, write out slab (f32) + bf16 h ----------------
__launch_bounds__(256)
__global__ void k_apply(const unsigned short* __restrict__ yb, const float* __restrict__ stl,
                        const float* __restrict__ g1, const float* __restrict__ b1,
                        const float* __restrict__ g2, const float* __restrict__ b2,
                        int layer, float* __restrict__ outl, unsigned int* __restrict__ hb,
                        int totalU8, float invN) {
    __shared__ float red[512];
    int tid = threadIdx.x;
    if (tid < 128) {
        float m1 = stl[tid] * invN;
        float v1 = stl[128 + tid] * invN - m1 * m1;
        float r1 = rsqrtf(v1 + 1e-5f);
        float s1 = g1[layer * 128 + tid] * r1;
        red[tid] = s1;
        red[128 + tid] = b1[layer * 128 + tid] - m1 * s1;
        float m2 = stl[256 + tid] * invN;
        float v2 = stl[384 + tid] * invN - m2 * m2;
        float r2 = rsqrtf(v2 + 1e-5f);
        float s2 = g2[layer * 128 + tid] * r2;
        red[256 + tid] = s2;
        red[384 + tid] = b2[layer * 128 + tid] - m2 * s2;
    }
    __syncthreads();
    int cbase = (8 * tid) & 127;
    float s1a[8], sh1a[8], s2a[8], sh2a[8];
    #pragma unroll
    for (int j = 0; j < 8; j++) {
        s1a[j]  = red[cbase + j];       sh1a[j] = red[128 + cbase + j];
        s2a[j]  = red[256 + cbase + j]; sh2a[j] = red[384 + cbase + j];
    }
    int gtid = blockIdx.x * 256 + tid;
    int gsz = gridDim.x * 256;
    const uint4* yb4 = (const uint4*)yb;
    for (int i = gtid; i < totalU8; i += gsz) {
        uint4 v = yb4[i];
        float f[8];
        f[0] = bf16lo(v.x); f[1] = bf16hi(v.x);
        f[2] = bf16lo(v.y); f[3] = bf16hi(v.y);
        f[4] = bf16lo(v.z); f[5] = bf16hi(v.z);
        f[6] = bf16lo(v.w); f[7] = bf16hi(v.w);
        float o[8];
        #pragma unroll
        for (int j = 0; j < 8; j++) {
            float t = fmaxf(f[j] * s1a[j] + sh1a[j], 0.f);
            o[j] = fmaxf(t * s2a[j] + sh2a[j], 0.f);
        }
        ((float4*)outl)[2 * i]     = make_float4(o[0], o[1], o[2], o[3]);
        ((float4*)outl)[2 * i + 1] = make_float4(o[4], o[5], o[6], o[7]);
        uint4 hbv;
        hbv.x = (unsigned int)f2bf(o[0]) | ((unsigned int)f2bf(o[1]) << 16);
        hbv.y = (unsigned int)f2bf(o[2]) | ((unsigned int)f2bf(o[3]) << 16);
        hbv.z = (unsigned int)f2bf(o[4]) | ((unsigned int)f2bf(o[5]) << 16);
        hbv.w = (unsigned int)f2bf(o[6]) | ((unsigned int)f2bf(o[7]) << 16);
        ((uint4*)hb)[i] = hbv;
    }
}

extern "C" void kernel_launch(void* const* d_in, const int* in_sizes, int n_in,
                              void* d_out, int out_size, void* d_ws, size_t ws_size,
                              hipStream_t stream) {
    const float* features = (const float*)d_in[0];
    const float* W        = (const float*)d_in[1];
    const float* bias     = (const float*)d_in[2];
    const float* eps      = (const float*)d_in[3];
    const float* g1       = (const float*)d_in[4];
    const float* b1       = (const float*)d_in[5];
    const float* g2       = (const float*)d_in[6];
    const float* b2       = (const float*)d_in[7];
    const int*   src      = (const int*)d_in[8];
    const int*   dst      = (const int*)d_in[9];

    const int Nn = in_sizes[0] / DD;   // 100000
    const int E  = in_sizes[8];        // 1600000
    float* out = (float*)d_out;

    char* w = (char*)d_ws;
    auto alloc = [&](size_t bytes) -> char* {
        char* p = w;
        w += (bytes + 255) & ~(size_t)255;
        return p;
    };
    // zero-span group (contiguous): deg, cursor, stats
    int*   deg    = (int*)alloc((size_t)Nn * 4);
    int*   cursor = (int*)alloc((size_t)Nn * 4);
    float* stats  = (float*)alloc(3 * 512 * 4);   // [3][4][128]
    char*  zero_end = w;
    int* row_start = (int*)alloc((size_t)(Nn + 1) * 4);
    int* partials  = (int*)alloc(1024);
    int* csr       = (int*)alloc((size_t)E * 4);
    unsigned int* hb = (unsigned int*)alloc((size_t)Nn * 64 * 4);
    unsigned int* zb = (unsigned int*)alloc((size_t)Nn * 64 * 4);
    unsigned short* Wt = (unsigned short*)alloc((size_t)3 * 128 * 128 * 2);
    unsigned short* yb = (unsigned short*)alloc((size_t)Nn * 128 * 2);

    const int total4 = Nn * DD / 4;
    const int totalU8 = Nn * DD / 8;
    const float invN = 1.0f / (float)Nn;
    const int nchunk = (Nn + 1023) / 1024;   // 98

    hipMemsetAsync(deg, 0, (size_t)(zero_end - (char*)deg), stream);

    k_setup<<<(E + 255) / 256, 256, 0, stream>>>(dst, deg, E, features, out, hb, total4, W, Wt);
    k_scan1<<<nchunk, 256, 0, stream>>>(deg, partials, Nn);
    k_scan3<<<nchunk, 256, 0, stream>>>(deg, partials, row_start, Nn, E, nchunk);
    k_scatter<<<(E + 255) / 256, 256, 0, stream>>>(src, dst, row_start, cursor, csr, E);

    for (int l = 0; l < 3; l++) {
        float* stl = stats + l * 512;
        float* outl = out + (size_t)(l + 1) * Nn * DD;
        k_gather<<<(Nn + 3) / 4, 256, 0, stream>>>(hb, row_start, csr, eps, l, zb, Nn);
        k_gemm<<<(Nn + 63) / 64, 256, 0, stream>>>((const unsigned short*)zb, Wt, bias, l, yb,
                                                   stl, Nn);
        k_stats2<<<512, 256, 0, stream>>>(yb, stl, g1, b1, l, totalU8, invN);
        k_apply<<<1024, 256, 0, stream>>>(yb, stl, g1, b1, g2, b2, l, outl, hb, totalU8, invN);
    }
}

// Round 3
// 833.845 us; speedup vs baseline: 1.1458x; 1.0360x over previous
//
#include <hip/hip_runtime.h>
#include <hip/hip_bf16.h>

#define DD 128

typedef __attribute__((ext_vector_type(8))) short bfrag8;
typedef __attribute__((ext_vector_type(4))) float f32x4;

__device__ __forceinline__ float bf16lo(unsigned int u) {
    union { unsigned int i; float f; } c; c.i = u << 16; return c.f;
}
__device__ __forceinline__ float bf16hi(unsigned int u) {
    union { unsigned int i; float f; } c; c.i = u & 0xffff0000u; return c.f;
}
__device__ __forceinline__ float bf16f(unsigned short u) {
    union { unsigned int i; float f; } c; c.i = ((unsigned int)u) << 16; return c.f;
}
__device__ __forceinline__ unsigned short f2bf(float f) {
    union { float f; unsigned int i; } c; c.f = f;
    unsigned int x = c.i;
    unsigned int r = (x + 0x7fffu + ((x >> 16) & 1u)) >> 16;  // RNE
    return (unsigned short)r;
}

// ---------------- setup: degree histogram + feature convert + W convert ----------------
__global__ void k_setup(const int* __restrict__ dst, int* __restrict__ deg, int E,
                        const float* __restrict__ features, float* __restrict__ out0,
                        unsigned int* __restrict__ hb, int total4,
                        const float* __restrict__ W, unsigned short* __restrict__ Wt) {
    int gtid = blockIdx.x * blockDim.x + threadIdx.x;
    int gsz = gridDim.x * blockDim.x;
    for (int i = gtid; i < E; i += gsz) atomicAdd(&deg[dst[i]], 1);
    for (int i = gtid; i < total4; i += gsz) {
        float4 v = ((const float4*)features)[i];
        ((float4*)out0)[i] = v;
        unsigned int lo = (unsigned int)f2bf(v.x) | ((unsigned int)f2bf(v.y) << 16);
        unsigned int hi = (unsigned int)f2bf(v.z) | ((unsigned int)f2bf(v.w) << 16);
        ((uint2*)hb)[i] = make_uint2(lo, hi);
    }
    for (int i = gtid; i < 3 * 128 * 128; i += gsz) {
        int l = i >> 14, r = i & 16383, k = r >> 7, n = r & 127;
        Wt[(l << 14) + n * 128 + k] = f2bf(W[i]);
    }
}

// ---------------- scan stage 1: per-1024-chunk degree sums ----------------
__global__ void k_scan1(const int* __restrict__ deg, int* __restrict__ partials, int Nn) {
    __shared__ int sm[256];
    int tid = threadIdx.x;
    int base = (blockIdx.x << 10) + 4 * tid;
    int s = 0;
    if (base + 3 < Nn) {
        int4 v = *(const int4*)&deg[base];
        s = v.x + v.y + v.z + v.w;
    } else {
        for (int j = 0; j < 4; j++) if (base + j < Nn) s += deg[base + j];
    }
    sm[tid] = s;
    __syncthreads();
    for (int off = 128; off > 0; off >>= 1) {
        if (tid < off) sm[tid] += sm[tid + off];
        __syncthreads();
    }
    if (tid == 0) partials[blockIdx.x] = sm[0];
}

// ---------------- scan stage 2: final row_start ----------------
__global__ void k_scan3(const int* __restrict__ deg, const int* __restrict__ partials,
                        int* __restrict__ row_start, int Nn, int E, int nchunk) {
    __shared__ int sp[256];
    __shared__ int sm[256];
    int tid = threadIdx.x, c = blockIdx.x;
    int p = (tid < nchunk) ? partials[tid] : 0;
    sp[tid] = p;
    __syncthreads();
    for (int off = 1; off < 256; off <<= 1) {
        int t = (tid >= off) ? sp[tid - off] : 0;
        __syncthreads();
        sp[tid] += t;
        __syncthreads();
    }
    int chunkpref = (c == 0) ? 0 : sp[c - 1];

    int base = (c << 10) + 4 * tid;
    int d0 = 0, d1 = 0, d2 = 0, d3 = 0;
    if (base + 3 < Nn) {
        int4 v = *(const int4*)&deg[base];
        d0 = v.x; d1 = v.y; d2 = v.z; d3 = v.w;
    } else {
        if (base + 0 < Nn) d0 = deg[base + 0];
        if (base + 1 < Nn) d1 = deg[base + 1];
        if (base + 2 < Nn) d2 = deg[base + 2];
        if (base + 3 < Nn) d3 = deg[base + 3];
    }
    int ts = d0 + d1 + d2 + d3;
    sm[tid] = ts;
    __syncthreads();
    for (int off = 1; off < 256; off <<= 1) {
        int t = (tid >= off) ? sm[tid - off] : 0;
        __syncthreads();
        sm[tid] += t;
        __syncthreads();
    }
    int run = chunkpref + sm[tid] - ts;
    if (base + 0 < Nn) row_start[base + 0] = run; run += d0;
    if (base + 1 < Nn) row_start[base + 1] = run; run += d1;
    if (base + 2 < Nn) row_start[base + 2] = run; run += d2;
    if (base + 3 < Nn) row_start[base + 3] = run;
    if (c == 0 && tid == 0) row_start[Nn] = E;
}

// ---------------- scatter edges into CSR ----------------
__global__ void k_scatter(const int* __restrict__ src, const int* __restrict__ dst,
                          const int* __restrict__ row_start, int* __restrict__ cursor,
                          int* __restrict__ csr, int E) {
    int i = blockIdx.x * blockDim.x + threadIdx.x;
    if (i < E) {
        int d = dst[i];
        int pos = row_start[d] + atomicAdd(&cursor[d], 1);
        csr[pos] = src[i];
    }
}

// ---------------- gather: z = (1+eps)*h + sum_{u in N(v)} h_u ----------------
// 1 wave per node. Lane layout: q = lane&15 owns an 8-column slice (16B);
// slot = lane>>4 owns one of 4 concurrent edges. One wave-instruction moves
// 1KB = 4 neighbor rows (vs 256B with dword loads) -> 4x MLP, 4x fewer issues.
__device__ __forceinline__ void acc_u4(float* acc, uint4 a) {
    acc[0] += bf16lo(a.x); acc[1] += bf16hi(a.x);
    acc[2] += bf16lo(a.y); acc[3] += bf16hi(a.y);
    acc[4] += bf16lo(a.z); acc[5] += bf16hi(a.z);
    acc[6] += bf16lo(a.w); acc[7] += bf16hi(a.w);
}

__global__ void k_gather(const unsigned int* __restrict__ hb, const int* __restrict__ row_start,
                         const int* __restrict__ csr, const float* __restrict__ eps, int layer,
                         unsigned int* __restrict__ zb, int Nn) {
    int wv = threadIdx.x >> 6, lane = threadIdx.x & 63;
    int v = blockIdx.x * 4 + wv;
    if (v >= Nn) return;
    int q = lane & 15;      // column slice: cols 8q..8q+7
    int slot = lane >> 4;   // edge slot 0..3
    const uint4* hb4 = (const uint4*)hb;
    float acc[8];
    #pragma unroll
    for (int j = 0; j < 8; j++) acc[j] = 0.f;

    int beg = row_start[v], end = row_start[v + 1];
    int e = beg;
    for (; e + 15 < end; e += 16) {
        int u0 = csr[e + slot];
        int u1 = csr[e + 4 + slot];
        int u2 = csr[e + 8 + slot];
        int u3 = csr[e + 12 + slot];
        uint4 a = hb4[(size_t)u0 * 16 + q];
        uint4 b = hb4[(size_t)u1 * 16 + q];
        uint4 c = hb4[(size_t)u2 * 16 + q];
        uint4 d = hb4[(size_t)u3 * 16 + q];
        acc_u4(acc, a); acc_u4(acc, b); acc_u4(acc, c); acc_u4(acc, d);
    }
    for (; e + 3 < end; e += 4) {
        int u = csr[e + slot];
        uint4 a = hb4[(size_t)u * 16 + q];
        acc_u4(acc, a);
    }
    {
        int r = end - e;   // 0..3 leftover edges
        if (slot < r) {
            int u = csr[e + slot];
            uint4 a = hb4[(size_t)u * 16 + q];
            acc_u4(acc, a);
        }
    }
    // cross-slot reduction: combine the 4 edge groups
    #pragma unroll
    for (int j = 0; j < 8; j++) {
        acc[j] += __shfl_xor(acc[j], 16);
        acc[j] += __shfl_xor(acc[j], 32);
    }
    if (slot == 0) {
        float e1 = 1.0f + eps[layer];
        uint4 hs = hb4[(size_t)v * 16 + q];
        float f0 = acc[0] + e1 * bf16lo(hs.x);
        float f1 = acc[1] + e1 * bf16hi(hs.x);
        float f2 = acc[2] + e1 * bf16lo(hs.y);
        float f3 = acc[3] + e1 * bf16hi(hs.y);
        float f4 = acc[4] + e1 * bf16lo(hs.z);
        float f5 = acc[5] + e1 * bf16hi(hs.z);
        float f6 = acc[6] + e1 * bf16lo(hs.w);
        float f7 = acc[7] + e1 * bf16hi(hs.w);
        uint4 o;
        o.x = (unsigned int)f2bf(f0) | ((unsigned int)f2bf(f1) << 16);
        o.y = (unsigned int)f2bf(f2) | ((unsigned int)f2bf(f3) << 16);
        o.z = (unsigned int)f2bf(f4) | ((unsigned int)f2bf(f5) << 16);
        o.w = (unsigned int)f2bf(f6) | ((unsigned int)f2bf(f7) << 16);
        ((uint4*)zb)[(size_t)v * 16 + q] = o;
    }
}

// ---------------- GEMM: y = z @ W + b (bf16 out), fused BN1 column stats ----------------
// LDS holds only the 64x128 A-tile. B fragments straight from global (W L2-resident).
__launch_bounds__(256)
__global__ void k_gemm(const unsigned short* __restrict__ zb, const unsigned short* __restrict__ Wt,
                       const float* __restrict__ bias, int layer, unsigned short* __restrict__ yb,
                       float* __restrict__ stl, int Nn) {
    __shared__ unsigned short Al[64 * 136];
    int tid = threadIdx.x;
    int m0 = blockIdx.x * 64;
    #pragma unroll
    for (int p = 0; p < 4; p++) {
        int slot = p * 256 + tid;
        int r = slot >> 4, c = slot & 15;
        int grow = m0 + r;
        uint4 val = make_uint4(0, 0, 0, 0);
        if (grow < Nn) val = *(const uint4*)&zb[(size_t)grow * 128 + c * 8];
        *(uint4*)&Al[r * 136 + c * 8] = val;
    }
    __syncthreads();

    int lane = tid & 63, wv = tid >> 6;
    int tcol = lane & 15, quad = lane >> 4;
    const unsigned short* Wl = Wt + (layer << 14);
    f32x4 acc[4][2];
    #pragma unroll
    for (int a = 0; a < 4; a++)
        #pragma unroll
        for (int b2 = 0; b2 < 2; b2++) acc[a][b2] = (f32x4){0.f, 0.f, 0.f, 0.f};

    #pragma unroll
    for (int kk = 0; kk < 128; kk += 32) {
        int kb = kk + quad * 8;
        bfrag8 af[4], bf[2];
        #pragma unroll
        for (int mt = 0; mt < 4; mt++)
            af[mt] = *(const bfrag8*)&Al[(16 * mt + tcol) * 136 + kb];
        #pragma unroll
        for (int nt = 0; nt < 2; nt++)
            bf[nt] = *(const bfrag8*)&Wl[(32 * wv + 16 * nt + tcol) * 128 + kb];
        #pragma unroll
        for (int mt = 0; mt < 4; mt++)
            #pragma unroll
            for (int nt = 0; nt < 2; nt++)
                acc[mt][nt] = __builtin_amdgcn_mfma_f32_16x16x32_bf16(af[mt], bf[nt], acc[mt][nt], 0, 0, 0);
    }

    // epilogue: bias, bf16 store, BN1 column stats (computed from ROUNDED values)
    #pragma unroll
    for (int nt = 0; nt < 2; nt++) {
        int col = 32 * wv + 16 * nt + tcol;
        float bcol = bias[layer * 128 + col];
        float psum = 0.f, psq = 0.f;
        #pragma unroll
        for (int mt = 0; mt < 4; mt++) {
            #pragma unroll
            for (int r = 0; r < 4; r++) {
                int row = m0 + 16 * mt + quad * 4 + r;
                if (row < Nn) {
                    unsigned short u = f2bf(acc[mt][nt][r] + bcol);
                    yb[(size_t)row * 128 + col] = u;
                    float vr = bf16f(u);
                    psum += vr;
                    psq += vr * vr;
                }
            }
        }
        psum += __shfl_xor(psum, 16); psq += __shfl_xor(psq, 16);
        psum += __shfl_xor(psum, 32); psq += __shfl_xor(psq, 32);
        if (lane < 16) {
            atomicAdd(&stl[col], psum);
            atomicAdd(&stl[128 + col], psq);
        }
    }
}

// ---------------- BN2 stats over relu(aff1(y)); BN1 scale/shift derived in-block ----------------
__launch_bounds__(256)
__global__ void k_stats2(const unsigned short* __restrict__ yb, float* __restrict__ stl,
                         const float* __restrict__ g1, const float* __restrict__ b1,
                         int layer, int totalU8, float invN) {
    __shared__ float red[512];
    int tid = threadIdx.x;
    if (tid < 128) {
        float m = stl[tid] * invN;
        float var = stl[128 + tid] * invN - m * m;
        float rstd = rsqrtf(var + 1e-5f);
        float s = g1[layer * 128 + tid] * rstd;
        red[tid] = s;
        red[128 + tid] = b1[layer * 128 + tid] - m * s;
        red[256 + tid] = 0.f;
        red[384 + tid] = 0.f;
    }
    __syncthreads();
    int lane = tid & 63;
    int cbase = (8 * tid) & 127;
    float s1r[8], sh1r[8];
    #pragma unroll
    for (int j = 0; j < 8; j++) { s1r[j] = red[cbase + j]; sh1r[j] = red[128 + cbase + j]; }
    float ps[8], pq[8];
    #pragma unroll
    for (int j = 0; j < 8; j++) { ps[j] = 0.f; pq[j] = 0.f; }
    int gtid = blockIdx.x * 256 + tid;
    int gsz = gridDim.x * 256;
    const uint4* yb4 = (const uint4*)yb;
    for (int i = gtid; i < totalU8; i += gsz) {
        uint4 v = yb4[i];
        float f[8];
        f[0] = bf16lo(v.x); f[1] = bf16hi(v.x);
        f[2] = bf16lo(v.y); f[3] = bf16hi(v.y);
        f[4] = bf16lo(v.z); f[5] = bf16hi(v.z);
        f[6] = bf16lo(v.w); f[7] = bf16hi(v.w);
        #pragma unroll
        for (int j = 0; j < 8; j++) {
            float t = fmaxf(f[j] * s1r[j] + sh1r[j], 0.f);
            ps[j] += t; pq[j] += t * t;
        }
    }
    #pragma unroll
    for (int j = 0; j < 8; j++) {
        ps[j] += __shfl_xor(ps[j], 16);
        pq[j] += __shfl_xor(pq[j], 16);
        ps[j] += __shfl_xor(ps[j], 32);
        pq[j] += __shfl_xor(pq[j], 32);
    }
    if (lane < 16) {
        #pragma unroll
        for (int j = 0; j < 8; j++) {
            atomicAdd(&red[256 + cbase + j], ps[j]);
            atomicAdd(&red[384 + cbase + j], pq[j]);
        }
    }
    __syncthreads();
    if (tid < 128) {
        atomicAdd(&stl[256 + tid], red[256 + tid]);
        atomicAdd(&stl[384 + tid], red[384 + tid]);
    }
}

// ---------------- apply both BNs, write out slab (f32) + bf16 h ----------------
__launch_bounds__(256)
__global__ void k_apply(const unsigned short* __restrict__ yb, const float* __restrict__ stl,
                        const float* __restrict__ g1, const float* __restrict__ b1,
                        const float* __restrict__ g2, const float* __restrict__ b2,
                        int layer, float* __restrict__ outl, unsigned int* __restrict__ hb,
                        int totalU8, float invN) {
    __shared__ float red[512];
    int tid = threadIdx.x;
    if (tid < 128) {
        float m1 = stl[tid] * invN;
        float v1 = stl[128 + tid] * invN - m1 * m1;
        float r1 = rsqrtf(v1 + 1e-5f);
        float s1 = g1[layer * 128 + tid] * r1;
        red[tid] = s1;
        red[128 + tid] = b1[layer * 128 + tid] - m1 * s1;
        float m2 = stl[256 + tid] * invN;
        float v2 = stl[384 + tid] * invN - m2 * m2;
        float r2 = rsqrtf(v2 + 1e-5f);
        float s2 = g2[layer * 128 + tid] * r2;
        red[256 + tid] = s2;
        red[384 + tid] = b2[layer * 128 + tid] - m2 * s2;
    }
    __syncthreads();
    int cbase = (8 * tid) & 127;
    float s1a[8], sh1a[8], s2a[8], sh2a[8];
    #pragma unroll
    for (int j = 0; j < 8; j++) {
        s1a[j]  = red[cbase + j];       sh1a[j] = red[128 + cbase + j];
        s2a[j]  = red[256 + cbase + j]; sh2a[j] = red[384 + cbase + j];
    }
    int gtid = blockIdx.x * 256 + tid;
    int gsz = gridDim.x * 256;
    const uint4* yb4 = (const uint4*)yb;
    for (int i = gtid; i < totalU8; i += gsz) {
        uint4 v = yb4[i];
        float f[8];
        f[0] = bf16lo(v.x); f[1] = bf16hi(v.x);
        f[2] = bf16lo(v.y); f[3] = bf16hi(v.y);
        f[4] = bf16lo(v.z); f[5] = bf16hi(v.z);
        f[6] = bf16lo(v.w); f[7] = bf16hi(v.w);
        float o[8];
        #pragma unroll
        for (int j = 0; j < 8; j++) {
            float t = fmaxf(f[j] * s1a[j] + sh1a[j], 0.f);
            o[j] = fmaxf(t * s2a[j] + sh2a[j], 0.f);
        }
        ((float4*)outl)[2 * i]     = make_float4(o[0], o[1], o[2], o[3]);
        ((float4*)outl)[2 * i + 1] = make_float4(o[4], o[5], o[6], o[7]);
        uint4 hbv;
        hbv.x = (unsigned int)f2bf(o[0]) | ((unsigned int)f2bf(o[1]) << 16);
        hbv.y = (unsigned int)f2bf(o[2]) | ((unsigned int)f2bf(o[3]) << 16);
        hbv.z = (unsigned int)f2bf(o[4]) | ((unsigned int)f2bf(o[5]) << 16);
        hbv.w = (unsigned int)f2bf(o[6]) | ((unsigned int)f2bf(o[7]) << 16);
        ((uint4*)hb)[i] = hbv;
    }
}

extern "C" void kernel_launch(void* const* d_in, const int* in_sizes, int n_in,
                              void* d_out, int out_size, void* d_ws, size_t ws_size,
                              hipStream_t stream) {
    const float* features = (const float*)d_in[0];
    const float* W        = (const float*)d_in[1];
    const float* bias     = (const float*)d_in[2];
    const float* eps      = (const float*)d_in[3];
    const float* g1       = (const float*)d_in[4];
    const float* b1       = (const float*)d_in[5];
    const float* g2       = (const float*)d_in[6];
    const float* b2       = (const float*)d_in[7];
    const int*   src      = (const int*)d_in[8];
    const int*   dst      = (const int*)d_in[9];

    const int Nn = in_sizes[0] / DD;   // 100000
    const int E  = in_sizes[8];        // 1600000
    float* out = (float*)d_out;

    char* w = (char*)d_ws;
    auto alloc = [&](size_t bytes) -> char* {
        char* p = w;
        w += (bytes + 255) & ~(size_t)255;
        return p;
    };
    // zero-span group (contiguous): deg, cursor, stats
    int*   deg    = (int*)alloc((size_t)Nn * 4);
    int*   cursor = (int*)alloc((size_t)Nn * 4);
    float* stats  = (float*)alloc(3 * 512 * 4);   // [3][4][128]
    char*  zero_end = w;
    int* row_start = (int*)alloc((size_t)(Nn + 1) * 4);
    int* partials  = (int*)alloc(1024);
    int* csr       = (int*)alloc((size_t)E * 4);
    unsigned int* hb = (unsigned int*)alloc((size_t)Nn * 64 * 4);
    unsigned int* zb = (unsigned int*)alloc((size_t)Nn * 64 * 4);
    unsigned short* Wt = (unsigned short*)alloc((size_t)3 * 128 * 128 * 2);
    unsigned short* yb = (unsigned short*)alloc((size_t)Nn * 128 * 2);

    const int total4 = Nn * DD / 4;
    const int totalU8 = Nn * DD / 8;
    const float invN = 1.0f / (float)Nn;
    const int nchunk = (Nn + 1023) / 1024;   // 98

    hipMemsetAsync(deg, 0, (size_t)(zero_end - (char*)deg), stream);

    k_setup<<<(E + 255) / 256, 256, 0, stream>>>(dst, deg, E, features, out, hb, total4, W, Wt);
    k_scan1<<<nchunk, 256, 0, stream>>>(deg, partials, Nn);
    k_scan3<<<nchunk, 256, 0, stream>>>(deg, partials, row_start, Nn, E, nchunk);
    k_scatter<<<(E + 255) / 256, 256, 0, stream>>>(src, dst, row_start, cursor, csr, E);

    for (int l = 0; l < 3; l++) {
        float* stl = stats + l * 512;
        float* outl = out + (size_t)(l + 1) * Nn * DD;
        k_gather<<<(Nn + 3) / 4, 256, 0, stream>>>(hb, row_start, csr, eps, l, zb, Nn);
        k_gemm<<<(Nn + 63) / 64, 256, 0, stream>>>((const unsigned short*)zb, Wt, bias, l, yb,
                                                   stl, Nn);
        k_stats2<<<512, 256, 0, stream>>>(yb, stl, g1, b1, l, totalU8, invN);
        k_apply<<<1024, 256, 0, stream>>>(yb, stl, g1, b1, g2, b2, l, outl, hb, totalU8, invN);
    }
}